// Round 2
// baseline (114.500 us; speedup 1.0000x reference)
//
#include <hip/hip_runtime.h>

// GauntTensorProductFixedParity — R8: single fused kernel, zero precompute launch.
//
// Reformulated pipeline (all per-block operand prep is pure swizzle, no FMA):
//   stage 1: c1 = in1·W1, c2 = in2·W2          [rows x 32]  (MFMA 16x16x32,
//            A = input frags (same loads as before), B = W frags from L1)
//   transpose c through per-wave LDS scratch (within-wave, no barrier)
//   stage 2: per p-tile pt: G1 = Y·c1^T, G2 = Y·c2^T  (MFMA 16x16x32, K=s)
//   H = G1 ⊙ G2 (f32->f16 in regs)
//   GEMM2:  out^T += Ywt·H  (MFMA 16x16x16, K=p)  — unchanged from R7,
//           exploiting C-layout == B-operand layout of the K=16 MFMA.
//
// Y-frags and Yw-frags are staged once per block into LDS by a cooperative
// swizzle (loads+cvt only). W-frags live in registers (8 x f16x8).
// Verified lane mappings reused from R7:
//   A-frag (m = lane&15, k = quad*8+j), B-frag (n = lane&15, k = quad*8+j),
//   C/D    (n = lane&15, m = quad*4+i).
//
// LDS: Yf [9][64][8]h = 9216B | Ywf [2][9][64][4]h = 9216B |
//      scratch [4 waves][2 ops][16][48]h = 12288B   -> 30720B total.
// Grid 512 x 256 thr, 256 rows/block, 4 waves x 4 row-tiles (64 rows/wave).

typedef _Float16 f16x8 __attribute__((ext_vector_type(8)));
typedef _Float16 f16x4 __attribute__((ext_vector_type(4)));
typedef float f32x4 __attribute__((ext_vector_type(4)));
typedef float f32x4u __attribute__((ext_vector_type(4), aligned(4)));

namespace {
constexpr int kD = 64, kS = 25, kP = 132;
constexpr int kBlock = 256, kM = 256;        // rows per block (4 waves x 64 rows)
constexpr int kYfOff  = 0;                   // [9][64][8] halfs   = 4608
constexpr int kYwOff  = 4608;                // [2][9][64][4] halfs = 4608
constexpr int kScrOff = 9216;                // [4][2][16][48] halfs = 6144
constexpr int kScrRow = 48;                  // padded row (96B, 16B-aligned, conflict-free b128)
constexpr int kLdsHalfs = 15360;             // 30720 B
}

__device__ __forceinline__ f16x8 ld8(const _Float16* p) {
    return *reinterpret_cast<const f16x8*>(p);
}
__device__ __forceinline__ f16x4 ld4(const _Float16* p) {
    return *reinterpret_cast<const f16x4*>(p);
}
__device__ __forceinline__ f16x8 cvt8h(f32x4 u, f32x4 v) {
    f16x8 r;
    r[0] = (_Float16)u[0]; r[1] = (_Float16)u[1];
    r[2] = (_Float16)u[2]; r[3] = (_Float16)u[3];
    r[4] = (_Float16)v[0]; r[5] = (_Float16)v[1];
    r[6] = (_Float16)v[2]; r[7] = (_Float16)v[3];
    return r;
}

__global__ __launch_bounds__(kBlock, 2) void gaunt_fused8(
    const float* __restrict__ in1, const float* __restrict__ in2,
    const float* __restrict__ W1, const float* __restrict__ W2,
    const float* __restrict__ Y,  const float* __restrict__ Yw,
    float* __restrict__ out)
{
    __shared__ _Float16 lds[kLdsHalfs];
    const int tid  = threadIdx.x;
    const int lane = tid & 63;
    const int w    = __builtin_amdgcn_readfirstlane(tid >> 6);
    const int lo16 = lane & 15, quad = lane >> 4;

    // ---- Phase 0a: Y A-frags -> LDS.  frag(pt,ln,j) = Y[pt*16+(ln&15)][(ln>>4)*8+j]
    for (int pair = tid; pair < 576; pair += kBlock) {
        const int pt = pair >> 6;                 // 0..8
        const int ln = pair & 63;
        const int p  = pt * 16 + (ln & 15);       // 0..143
        const int s0 = ((ln >> 4) & 3) * 8;       // 0,8,16,24
        f16x8 v;
        #pragma unroll
        for (int j = 0; j < 8; ++j) v[j] = (_Float16)0.f;
        if (p < kP) {
            const float* yp = Y + p * kS + s0;
            if (s0 < 24) {                        // s0 in {0,8,16}: all 8 valid
                const f32x4u u = *reinterpret_cast<const f32x4u*>(yp);
                const f32x4u q = *reinterpret_cast<const f32x4u*>(yp + 4);
                #pragma unroll
                for (int j = 0; j < 4; ++j) {
                    v[j]     = (_Float16)u[j];
                    v[4 + j] = (_Float16)q[j];
                }
            } else {                              // s0 == 24: only s=24 valid
                v[0] = (_Float16)yp[0];
            }
        }
        *reinterpret_cast<f16x8*>(&lds[kYfOff + (pt * 64 + ln) * 8]) = v;
    }

    // ---- Phase 0b: Ywt A-frags (K=16) -> LDS.  Ywt[s][p] = Yw[p][s]
    for (int e = tid; e < 4608; e += kBlock) {
        const int i = e & 3, ln = (e >> 2) & 63, r = e >> 8;  // r 0..17
        const int pt = r % 9, st = r / 9;
        const int p = pt * 16 + ((ln >> 4) & 3) * 4 + i;      // 0..143
        const int s = st * 16 + (ln & 15);                    // 0..31
        lds[kYwOff + e] = (s < kS && p < kP) ? (_Float16)Yw[p * kS + s]
                                             : (_Float16)0.f;
    }

    // ---- Phase 0c: W B-frags -> registers.  B(n=s local, k=d local) = W[d][s]
    f16x8 w1f[2][2], w2f[2][2];                   // [st][ks]
    #pragma unroll
    for (int st = 0; st < 2; ++st) {
        const int s = st * 16 + lo16;
        #pragma unroll
        for (int ks = 0; ks < 2; ++ks) {
            f16x8 a, b;
            #pragma unroll
            for (int j = 0; j < 8; ++j) { a[j] = (_Float16)0.f; b[j] = (_Float16)0.f; }
            if (s < kS) {
                const int d0 = ks * 32 + quad * 8;
                #pragma unroll
                for (int j = 0; j < 8; ++j) {
                    a[j] = (_Float16)W1[(d0 + j) * kS + s];
                    b[j] = (_Float16)W2[(d0 + j) * kS + s];
                }
            }
            w1f[st][ks] = a; w2f[st][ks] = b;
        }
    }

    __syncthreads();

    // ---- input A-frags: lane m=row=lo16, k=d=ks*32+quad*8+j ----
    const long long base = (long long)blockIdx.x * (kM * kD);
    f16x8 b1[4][2], b2[4][2];
    #pragma unroll
    for (int rt = 0; rt < 4; ++rt) {
        const int row = (4 * w + rt) * 16 + lo16;
        const float* p1 = in1 + base + row * kD + quad * 8;
        const float* p2 = in2 + base + row * kD + quad * 8;
        #pragma unroll
        for (int ks = 0; ks < 2; ++ks) {
            const f32x4 u1 = *reinterpret_cast<const f32x4*>(p1 + ks * 32);
            const f32x4 v1 = *reinterpret_cast<const f32x4*>(p1 + ks * 32 + 4);
            const f32x4 u2 = *reinterpret_cast<const f32x4*>(p2 + ks * 32);
            const f32x4 v2 = *reinterpret_cast<const f32x4*>(p2 + ks * 32 + 4);
            b1[rt][ks] = cvt8h(u1, v1);
            b2[rt][ks] = cvt8h(u2, v2);
        }
    }

    // ---- Stage 1: c = in·W (C: lane holds s=lo16(+st*16), n_row=quad*4+i),
    //      then transpose via per-wave LDS scratch to B-frags (n=lo16, k=s).
    f16x8 c1t[4], c2t[4];
    _Float16* scr = &lds[kScrOff + w * (2 * 16 * kScrRow)];
    #pragma unroll
    for (int rt = 0; rt < 4; ++rt) {
        f32x4 c1[2], c2[2];
        #pragma unroll
        for (int st = 0; st < 2; ++st) {
            c1[st] = (f32x4){0.f, 0.f, 0.f, 0.f};
            c2[st] = (f32x4){0.f, 0.f, 0.f, 0.f};
        }
        #pragma unroll
        for (int st = 0; st < 2; ++st)
            #pragma unroll
            for (int ks = 0; ks < 2; ++ks) {
                c1[st] = __builtin_amdgcn_mfma_f32_16x16x32_f16(b1[rt][ks], w1f[st][ks], c1[st], 0, 0, 0);
                c2[st] = __builtin_amdgcn_mfma_f32_16x16x32_f16(b2[rt][ks], w2f[st][ks], c2[st], 0, 0, 0);
            }
        #pragma unroll
        for (int st = 0; st < 2; ++st)
            #pragma unroll
            for (int i = 0; i < 4; ++i) {
                scr[(quad * 4 + i) * kScrRow + st * 16 + lo16]       = (_Float16)c1[st][i];
                scr[768 + (quad * 4 + i) * kScrRow + st * 16 + lo16] = (_Float16)c2[st][i];
            }
        c1t[rt] = ld8(&scr[lo16 * kScrRow + quad * 8]);
        c2t[rt] = ld8(&scr[768 + lo16 * kScrRow + quad * 8]);
    }

    // ---- Stage 2 + GEMM2 over 9 p-tiles, Y/Yw frags double-buffered from LDS
    f32x4 oacc[4][2];
    #pragma unroll
    for (int rt = 0; rt < 4; ++rt)
        #pragma unroll
        for (int st = 0; st < 2; ++st)
            oacc[rt][st] = (f32x4){0.f, 0.f, 0.f, 0.f};

    f16x8 yc  = ld8(&lds[kYfOff + lane * 8]);
    f16x4 yw0 = ld4(&lds[kYwOff + lane * 4]);
    f16x4 yw1 = ld4(&lds[kYwOff + 9 * 256 + lane * 4]);

    #pragma unroll 1
    for (int pt = 0; pt < 9; ++pt) {
        f16x8 yn; f16x4 yw0n, yw1n;
        if (pt < 8) {
            yn   = ld8(&lds[kYfOff + (pt + 1) * 512 + lane * 8]);
            yw0n = ld4(&lds[kYwOff + (pt + 1) * 256 + lane * 4]);
            yw1n = ld4(&lds[kYwOff + (9 + pt + 1) * 256 + lane * 4]);
        }
        #pragma unroll
        for (int rt = 0; rt < 4; ++rt) {
            f32x4 z = (f32x4){0.f, 0.f, 0.f, 0.f};
            f32x4 g1 = __builtin_amdgcn_mfma_f32_16x16x32_f16(yc, c1t[rt], z, 0, 0, 0);
            f32x4 g2 = __builtin_amdgcn_mfma_f32_16x16x32_f16(yc, c2t[rt], z, 0, 0, 0);
            f16x4 h;
            h[0] = (_Float16)(g1[0] * g2[0]);
            h[1] = (_Float16)(g1[1] * g2[1]);
            h[2] = (_Float16)(g1[2] * g2[2]);
            h[3] = (_Float16)(g1[3] * g2[3]);
            oacc[rt][0] = __builtin_amdgcn_mfma_f32_16x16x16f16(yw0, h, oacc[rt][0], 0, 0, 0);
            oacc[rt][1] = __builtin_amdgcn_mfma_f32_16x16x16f16(yw1, h, oacc[rt][1], 0, 0, 0);
        }
        yc = yn; yw0 = yw0n; yw1 = yw1n;
    }

    // ---- stores: out^T C-layout -> per-lane 16B-contiguous runs ----
    const long long ob = (long long)blockIdx.x * (kM * kS);
    #pragma unroll
    for (int rt = 0; rt < 4; ++rt) {
        const int row = (4 * w + rt) * 16 + lo16;
        float* rp = out + ob + (long long)row * kS;
        // st=0: s = quad*4 + i, 0..15 all valid
        *reinterpret_cast<f32x4u*>(rp + quad * 4) = oacc[rt][0];
        // st=1: s = 16 + quad*4 + i, valid while < 25
        if (quad < 2) {
            *reinterpret_cast<f32x4u*>(rp + 16 + quad * 4) = oacc[rt][1];
        } else if (quad == 2) {
            rp[24] = oacc[rt][1][0];
        }
    }
}

extern "C" void kernel_launch(void* const* d_in, const int* in_sizes, int n_in,
                              void* d_out, int out_size, void* d_ws, size_t ws_size,
                              hipStream_t stream) {
    const float* in1 = (const float*)d_in[0];   // [N, 64]
    const float* in2 = (const float*)d_in[1];   // [N, 64]
    const float* W1  = (const float*)d_in[2];   // [64, 25]
    const float* W2  = (const float*)d_in[3];   // [64, 25]
    const float* Y   = (const float*)d_in[4];   // [132, 25]
    const float* Yw  = (const float*)d_in[5];   // [132, 25]
    float* out = (float*)d_out;                 // [N, 25]
    (void)d_ws; (void)ws_size;

    const int n_rows = in_sizes[0] / kD;        // 131072
    const int grid = n_rows / kM;               // 512
    gaunt_fused8<<<grid, kBlock, 0, stream>>>(in1, in2, W1, W2, Y, Yw, out);
}